// Round 21
// baseline (26.984 us; speedup 1.0000x reference)
//
#include <hip/hip_runtime.h>

// LBP forward: out[n,f,h,w] = sum_p 2^p * sigmoid((nb - ctr)/0.1)
//   c  = projection_map[f,p]; ky,kx = kernels[f,p,:] in {0,1,2}
//   nb  = xpad[n,c,h+ky-1,w+kx-1]  (zero pad of 1), ctr = x[n,c,h,w]
// N=32 D=64 H=56 W=56 F=128 P=4
//
// Round-21 = r20 skeleton with ONLY the compute mapping changed (clean A/B).
// r20's compute = 3584 wave-LDS instrs/CU (ds_read2, 8B payload) ~ 13us of
// LDS issue. New mapping: lane = (r = lane>>4, g = lane&15); each lane owns
// 4 COLUMNS x 1 row x 2 images via ds_read_b128 (quarter-wave = contiguous
// 256B -> conflict-free). 1 dword = 1 image-pair column, so the kx shift is
// a whole-dword WINDOW over 2 aligned b128s (M reused from ctr when ky==1),
// picked by register naming - zero VALU. Per non-center p: 2-3 b128 vs 8
// ds_read2 -> ~8.5 vs 28 LDS instrs per f-iter (3.3x fewer, 4x payload).
// Pads widened to cols 0..3 / 60..63 so windows never leave the tile.
// Stores: global_store_dwordx4 (4 cols) x 2 images per lane per f-iter.
// Tile: fp16 half2 packed across images (n, n+16), identical indexing both
// halves (r19-proven). Center taps fold to wt/2 in acc init. Sigmoid:
// 3-tangent-line min in packed v_pk_fma/min_f16 (absmax 0.1875 proven).

#define NN 32
#define DD 64
#define HH 56
#define WW 56
#define FF 128
#define PP 4

#define ROWS 4          // output rows per block
#define TR   (ROWS + 2) // 6 tile rows incl. halo
#define TC   64         // cols: pads 0..3 and 60..63, data 4..59
#define COL0 4
#define CHS  (TR * TC)  // 384 dwords per channel (dword = half2 image-pair)
#define TILE_DW (DD * CHS)   // 24576 dwords = 98304 B
#define NTHREADS 1024
#define NWAVES 16
#define NPAIR 16
#define NSTRIP (HH / ROWS)       // 14
#define FITER (FF / NWAVES)      // 8 f per wave
#define ITEMS (DD * TR * 14)     // 5376 staging items (2 float4 loads each)
#define NSLOT 6
#define IMGSTR (DD * HH * WW)    // floats per image

typedef _Float16 h2 __attribute__((ext_vector_type(2)));

static __device__ __forceinline__ uint32_t h2u(h2 h) {
    union { h2 h; uint32_t u; } v; v.h = h; return v.u;
}
static __device__ __forceinline__ h2 u2h(uint32_t u) {
    union { h2 h; uint32_t u; } v; v.u = u; return v.h;
}
static __device__ __forceinline__ h2 splat(float f) {
    h2 r; r.x = (_Float16)f; r.y = (_Float16)f; return r;
}
static __device__ __forceinline__ uint32_t pack2(float a, float b) {
    h2 r; r.x = (_Float16)a; r.y = (_Float16)b; return h2u(r);
}

__global__ __launch_bounds__(NTHREADS, 4) void lbp_kernel(
    const float* __restrict__ x,    // (N,D,H,W)
    const int*   __restrict__ kern, // (F,P,2)
    const int*   __restrict__ proj, // (F,P)
    float*       __restrict__ out)  // (N,F,H,W)
{
    __shared__ uint32_t tile[TILE_DW];   // 98304 B, 1 block/CU

    const int tid = threadIdx.x;
    const int pr  = blockIdx.x;          // pair: images (pr, pr+16); XCD pin
    const int h0  = blockIdx.y * ROWS;   // 0,4,...,52

    const float* x0 = x + (size_t)pr * IMGSTR;
    const float* x1 = x0 + (size_t)NPAIR * IMGSTR;

    // ---- stage: 5376 items, 2 float4 loads each, all issued up front ----
    float4 av[NSLOT], bv[NSLOT];
    int    lo[NSLOT];
#pragma unroll
    for (int it = 0; it < NSLOT; ++it) {
        const int item = tid + it * NTHREADS;
        av[it] = make_float4(0.f, 0.f, 0.f, 0.f);
        bv[it] = make_float4(0.f, 0.f, 0.f, 0.f);
        lo[it] = -1;
        if (item < ITEMS) {                       // only it==5 is partial
            const int ch  = item / (TR * 14);
            const int rem = item - ch * (TR * 14);
            const int tr  = rem / 14;
            const int v   = rem - tr * 14;
            lo[it] = ch * CHS + tr * TC + COL0 + 4 * v;
            const int h = h0 + tr - 1;
            if ((unsigned)h < (unsigned)HH) {
                const int off = ch * (HH * WW) + h * WW + 4 * v;
                av[it] = *(const float4*)(x0 + off);
                bv[it] = *(const float4*)(x1 + off);
            }
        }
    }

    // ---- zero pad cols 0..3 and 60..63 (b128 each) while loads fly ----
    if (tid < DD * TR * 2) {
        const int side = tid & 1;
        const int cr   = tid >> 1;               // ch*TR + tr, 0..383
        *(uint4*)(tile + cr * TC + (side ? 60 : 0)) =
            make_uint4(0u, 0u, 0u, 0u);
    }

    // ---- pack (img0 = lo half, img1 = hi half) and land b128 ----
#pragma unroll
    for (int it = 0; it < NSLOT; ++it) {
        if (lo[it] >= 0) {
            uint4 q;
            q.x = pack2(av[it].x, bv[it].x);
            q.y = pack2(av[it].y, bv[it].y);
            q.z = pack2(av[it].z, bv[it].z);
            q.w = pack2(av[it].w, bv[it].w);
            *(uint4*)(tile + lo[it]) = q;        // 16B aligned (COL0+4v)
        }
    }
    __syncthreads();

    // ---- compute: wave = f-group; lane = (row, 4-col group) ----
    const int wid  = __builtin_amdgcn_readfirstlane(tid >> 6);  // 0..15
    const int lane = tid & 63;
    const int r    = lane >> 4;          // 0..3   output row within strip
    const int g    = lane & 15;          // 0..15  col group (4 cols)
    const bool act = g < 14;             // 14 groups cover 56 cols
    const int gc   = act ? g : 13;       // clamp idle lanes' addresses
    const int colb = COL0 + 4 * gc;      // aligned dword col of group base

    const h2 K0a = splat(2.5f),     K0b = splat(-0.0078f);
    const h2 K1a = splat(1.49146f), K1b = splat(0.08455f);
    const h2 K2a = splat(0.45177f), K2b = splat(0.30774f);
    const h2 KF  = splat(0.49140f);
    const h2 INI = splat(7.5f);          // sum wt*0.5 over all taps

    int f = wid;
    int4 pj = *(const int4*)(proj + f * PP);
    int4 ka = *(const int4*)(kern + f * (PP * 2));
    int4 kb = *(const int4*)(kern + f * (PP * 2) + 4);

#pragma unroll
    for (int k = 0; k < FITER; ++k) {
        const int fn = f + NWAVES;
        int4 pjn = pj, kan = ka, kbn = kb;       // initialized (no UB)
        if (k + 1 < FITER) {                     // one-ahead table prefetch
            pjn = *(const int4*)(proj + fn * PP);
            kan = *(const int4*)(kern + fn * (PP * 2));
            kbn = *(const int4*)(kern + fn * (PP * 2) + 4);
        }
        const int cc[4]  = {pj.x, pj.y, pj.z, pj.w};
        const int kyv[4] = {ka.x, ka.z, kb.x, kb.z};
        const int kxv[4] = {ka.y, ka.w, kb.y, kb.w};

        h2 acc[4];
#pragma unroll
        for (int j = 0; j < 4; ++j) acc[j] = INI;

#pragma unroll
        for (int p = 0; p < PP; ++p) {
            const int ky = kyv[p];               // wave-uniform (SGPR)
            const int kx = kxv[p];
            if (ky == 1 && kx == 1) continue;    // center tap exact in INI

            const int cbase = cc[p] * CHS + (1 + r) * TC + colb;
            const uint4 C = *(const uint4*)(tile + cbase);       // ctr 4 cols
            const int nrow = cc[p] * CHS + (ky + r) * TC;

            uint32_t n0, n1, n2, n3;
            if (kx == 1) {                       // ky != 1 here
                const uint4 M = *(const uint4*)(tile + nrow + colb);
                n0 = M.x; n1 = M.y; n2 = M.z; n3 = M.w;
            } else if (kx == 0) {                // shift left by one column
                const uint4 L = *(const uint4*)(tile + nrow + colb - 4);
                uint4 M;
                if (ky == 1) M = C;
                else M = *(const uint4*)(tile + nrow + colb);
                n0 = L.w; n1 = M.x; n2 = M.y; n3 = M.z;
            } else {                             // kx == 2: shift right
                uint4 M;
                if (ky == 1) M = C;
                else M = *(const uint4*)(tile + nrow + colb);
                const uint4 R = *(const uint4*)(tile + nrow + colb + 4);
                n0 = M.y; n1 = M.z; n2 = M.w; n3 = R.x;
            }

            const uint32_t cu4[4] = {C.x, C.y, C.z, C.w};
            const uint32_t nu4[4] = {n0, n1, n2, n3};
            const h2 wt2 = splat((float)(1 << p));
#pragma unroll
            for (int j = 0; j < 4; ++j) {
                const h2 d  = u2h(nu4[j]) - u2h(cu4[j]);
                const uint32_t du = h2u(d);
                const h2 ad = u2h(du & 0x7FFF7FFFu);
                const h2 u0 = __builtin_elementwise_fma(K0a, ad, K0b);
                const h2 u1 = __builtin_elementwise_fma(K1a, ad, K1b);
                const h2 u2 = __builtin_elementwise_fma(K2a, ad, K2b);
                const h2 um = __builtin_elementwise_min(
                                  __builtin_elementwise_min(u0, u1),
                                  __builtin_elementwise_min(u2, KF));
                const uint32_t su = (du & 0x80008000u)
                                  | (h2u(um) & 0x7FFF7FFFu);
                acc[j] = __builtin_elementwise_fma(wt2, u2h(su), acc[j]);
            }
        }

        if (act) {
            float* o0 = out + ((size_t)pr * FF + f) * (HH * WW)
                            + (h0 + r) * WW + 4 * g;
            *(float4*)o0 = make_float4((float)acc[0].x, (float)acc[1].x,
                                       (float)acc[2].x, (float)acc[3].x);
            float* o1 = o0 + (size_t)NPAIR * FF * (HH * WW);
            *(float4*)o1 = make_float4((float)acc[0].y, (float)acc[1].y,
                                       (float)acc[2].y, (float)acc[3].y);
        }
        f = fn; pj = pjn; ka = kan; kb = kbn;
    }
}

extern "C" void kernel_launch(void* const* d_in, const int* in_sizes, int n_in,
                              void* d_out, int out_size, void* d_ws, size_t ws_size,
                              hipStream_t stream) {
    const float* x    = (const float*)d_in[0];
    const int*   kern = (const int*)d_in[1];
    const int*   proj = (const int*)d_in[2];
    float*       out  = (float*)d_out;

    dim3 grid(NPAIR, NSTRIP);   // x = pair (XCD pin: id%8 = pair%8), y = strip
    dim3 block(NTHREADS);
    lbp_kernel<<<grid, block, 0, stream>>>(x, kern, proj, out);
}

// Round 22
// 25.952 us; speedup vs baseline: 1.0398x; 1.0398x over previous
//
#include <hip/hip_runtime.h>

// LBP forward: out[n,f,h,w] = sum_p 2^p * sigmoid((nb - ctr)/0.1)
//   c  = projection_map[f,p]; ky,kx = kernels[f,p,:] in {0,1,2}
//   nb  = xpad[n,c,h+ky-1,w+kx-1]  (zero pad of 1), ctr = x[n,c,h,w]
// N=32 D=64 H=56 W=56 F=128 P=4
//
// Round-22: combine the three proven win factors that never coexisted:
//   (1) fp16 image-pair packing (r19: the only real gain, -2.2us),
//   (2) near-single-fetch staging (r20: 44MB here vs r19's 66MB),
//   (3) 256 blocks = full CU coverage (r19; r20 had only 224).
// Trick: replace r19's f-split (which double-fetched every tile) with an
// ASYMMETRIC ROW-SPLIT: grid = 16 pairs x 8 strips x 2 halves. Half 0 owns
// output rows 0..3 of the 7-row strip, half 1 rows 4..6. Both halves run
// r20's IDENTICAL 6-tile-row code (h-base shifted by 4); half 1 just masks
// row 3 at store. Twins sit on the same XCD (linear id delta = 128 -> same
// id%8), so their 2 overlapping halo rows are L2-local. All 256 blocks have
// identical cost (no tail).
// Center taps (ky==kx==1) fold to wt/2 in acc init; reads+math skipped.
// Sigmoid: 3-tangent-line min in packed v_pk_fma/min_f16 (0.1875 proven).

#define NN 32
#define DD 64
#define HH 56
#define WW 56
#define FF 128
#define PP 4

#define ROWS 4          // computed rows per block (half 1 stores only 3)
#define TR   (ROWS + 2) // 6 tile rows incl. halo
#define TC   64         // padded cols (interior 4..59, zero pads at 3 and 60)
#define COL0 4
#define CHS  (TR * TC)  // 384 dwords per channel (dword = half2 image-pair)
#define TILE_DW (DD * CHS)   // 24576 dwords = 98304 B
#define NTHREADS 1024
#define NWAVES 16
#define NPAIR 16
#define NSTRIP 8                 // strips of 7 output rows
#define FITER (FF / NWAVES)      // 8 f per wave
#define ITEMS (DD * TR * 14)     // 5376 staging items (2 float4 loads each)
#define NSLOT 6
#define IMGSTR (DD * HH * WW)    // floats per image

typedef _Float16 h2 __attribute__((ext_vector_type(2)));

static __device__ __forceinline__ uint32_t h2u(h2 h) {
    union { h2 h; uint32_t u; } v; v.h = h; return v.u;
}
static __device__ __forceinline__ h2 u2h(uint32_t u) {
    union { h2 h; uint32_t u; } v; v.u = u; return v.h;
}
static __device__ __forceinline__ h2 splat(float f) {
    h2 r; r.x = (_Float16)f; r.y = (_Float16)f; return r;
}
static __device__ __forceinline__ uint32_t pack2(float a, float b) {
    h2 r; r.x = (_Float16)a; r.y = (_Float16)b; return h2u(r);
}

__global__ __launch_bounds__(NTHREADS, 4) void lbp_kernel(
    const float* __restrict__ x,    // (N,D,H,W)
    const int*   __restrict__ kern, // (F,P,2)
    const int*   __restrict__ proj, // (F,P)
    float*       __restrict__ out)  // (N,F,H,W)
{
    __shared__ uint32_t tile[TILE_DW];   // 98304 B, 1 block/CU

    const int tid   = threadIdx.x;
    const int pr    = blockIdx.x;        // pair: images (pr, pr+16); XCD pin
    const int strip = blockIdx.y;        // 0..7
    const int half  = blockIdx.z;        // 0..1
    const int hbase = strip * 7 + half * 4;   // first output row of block
    const int nrows = half ? 3 : ROWS;        // stored rows

    const float* x0 = x + (size_t)pr * IMGSTR;
    const float* x1 = x0 + (size_t)NPAIR * IMGSTR;

    // ---- stage: 5376 items, 2 float4 loads each, all issued up front ----
    float4 av[NSLOT], bv[NSLOT];
    int    lo[NSLOT];
#pragma unroll
    for (int it = 0; it < NSLOT; ++it) {
        const int item = tid + it * NTHREADS;
        av[it] = make_float4(0.f, 0.f, 0.f, 0.f);
        bv[it] = make_float4(0.f, 0.f, 0.f, 0.f);
        lo[it] = -1;
        if (item < ITEMS) {                       // only it==5 is partial
            const int ch  = item / (TR * 14);
            const int rem = item - ch * (TR * 14);
            const int tr  = rem / 14;
            const int v   = rem - tr * 14;
            lo[it] = ch * CHS + tr * TC + COL0 + 4 * v;
            const int h = hbase + tr - 1;         // covers both OOB ends
            if ((unsigned)h < (unsigned)HH) {
                const int off = ch * (HH * WW) + h * WW + 4 * v;
                av[it] = *(const float4*)(x0 + off);
                bv[it] = *(const float4*)(x1 + off);
            }
        }
    }

    // ---- zero the kx-pad columns (3 and 60) while loads fly ----
    if (tid < DD * TR * 2) {
        const int side = tid & 1;
        const int cr   = tid >> 1;               // ch*TR + tr
        tile[cr * TC + (side ? 60 : 3)] = 0u;
    }

    // ---- pack (img0 = lo half, img1 = hi half) and land b128 ----
#pragma unroll
    for (int it = 0; it < NSLOT; ++it) {
        if (lo[it] >= 0) {
            uint4 q;
            q.x = pack2(av[it].x, bv[it].x);
            q.y = pack2(av[it].y, bv[it].y);
            q.z = pack2(av[it].z, bv[it].z);
            q.w = pack2(av[it].w, bv[it].w);
            *(uint4*)(tile + lo[it]) = q;        // 16B aligned (COL0+4v)
        }
    }
    __syncthreads();

    // ---- compute: wave = f-group, lane = column, 4 rows x 2 images ----
    const int wid  = __builtin_amdgcn_readfirstlane(tid >> 6);  // 0..15
    const int lane = tid & 63;
    const int w    = lane < WW ? lane : WW - 1;  // clamp idle lanes
    const bool act = lane < WW;
    const int cb   = TC + COL0 + w;              // ctr addr of output row 0

    const h2 K0a = splat(2.5f),     K0b = splat(-0.0078f);
    const h2 K1a = splat(1.49146f), K1b = splat(0.08455f);
    const h2 K2a = splat(0.45177f), K2b = splat(0.30774f);
    const h2 KF  = splat(0.49140f);
    const h2 INI = splat(7.5f);                  // sum wt*0.5 over all taps

    int f = wid;
    int4 pj = *(const int4*)(proj + f * PP);
    int4 ka = *(const int4*)(kern + f * (PP * 2));
    int4 kb = *(const int4*)(kern + f * (PP * 2) + 4);

#pragma unroll
    for (int k = 0; k < FITER; ++k) {
        const int fn = f + NWAVES;
        int4 pjn = pj, kan = ka, kbn = kb;       // initialized (no UB)
        if (k + 1 < FITER) {                     // one-ahead table prefetch
            pjn = *(const int4*)(proj + fn * PP);
            kan = *(const int4*)(kern + fn * (PP * 2));
            kbn = *(const int4*)(kern + fn * (PP * 2) + 4);
        }
        const int cc[4]  = {pj.x, pj.y, pj.z, pj.w};
        const int kyv[4] = {ka.x, ka.z, kb.x, kb.z};
        const int kxv[4] = {ka.y, ka.w, kb.y, kb.w};

        // ---- bulk packed reads: skip center taps; one lgkmcnt join ----
        uint32_t cu[PP][ROWS], nu[PP][ROWS];
#pragma unroll
        for (int p = 0; p < PP; ++p) {
            const int ky = kyv[p];               // wave-uniform
            const int kx = kxv[p];
            if (!(ky == 1 && kx == 1)) {
                const int pc = cc[p] * CHS + cb;               // ctr row 0
                const int pn = pc + (ky - 1) * TC + (kx - 1);  // neighbor
#pragma unroll
                for (int r = 0; r < ROWS; ++r) {
                    cu[p][r] = tile[pc + r * TC];
                    nu[p][r] = tile[pn + r * TC];
                }
            }
        }

        // ---- packed trans-free sigmoid ----
        h2 acc[ROWS];
#pragma unroll
        for (int r = 0; r < ROWS; ++r) acc[r] = INI;
#pragma unroll
        for (int p = 0; p < PP; ++p) {
            if (!(kyv[p] == 1 && kxv[p] == 1)) {
                const h2 wt2 = splat((float)(1 << p));
#pragma unroll
                for (int r = 0; r < ROWS; ++r) {
                    const h2 d  = u2h(nu[p][r]) - u2h(cu[p][r]);
                    const uint32_t du = h2u(d);
                    const h2 ad = u2h(du & 0x7FFF7FFFu);
                    const h2 u0 = __builtin_elementwise_fma(K0a, ad, K0b);
                    const h2 u1 = __builtin_elementwise_fma(K1a, ad, K1b);
                    const h2 u2 = __builtin_elementwise_fma(K2a, ad, K2b);
                    const h2 um = __builtin_elementwise_min(
                                      __builtin_elementwise_min(u0, u1),
                                      __builtin_elementwise_min(u2, KF));
                    const uint32_t su = (du & 0x80008000u)
                                      | (h2u(um) & 0x7FFF7FFFu);
                    acc[r] = __builtin_elementwise_fma(wt2, u2h(su), acc[r]);
                }
            }
        }

        if (act) {
            float* o0 = out + ((size_t)pr * FF + f) * (HH * WW)
                            + (size_t)hbase * WW + w;
            float* o1 = o0 + (size_t)NPAIR * FF * (HH * WW);
#pragma unroll
            for (int r = 0; r < ROWS; ++r) {
                if (r < nrows) {                 // half 1 masks row 3
                    o0[r * WW] = (float)acc[r].x;
                    o1[r * WW] = (float)acc[r].y;
                }
            }
        }
        f = fn; pj = pjn; ka = kan; kb = kbn;
    }
}

extern "C" void kernel_launch(void* const* d_in, const int* in_sizes, int n_in,
                              void* d_out, int out_size, void* d_ws, size_t ws_size,
                              hipStream_t stream) {
    const float* x    = (const float*)d_in[0];
    const int*   kern = (const int*)d_in[1];
    const int*   proj = (const int*)d_in[2];
    float*       out  = (float*)d_out;

    dim3 grid(NPAIR, NSTRIP, 2);   // 16 x 8 x 2 = 256 blocks = 1/CU
    dim3 block(NTHREADS);
    lbp_kernel<<<grid, block, 0, stream>>>(x, kern, proj, out);
}

// Round 23
// 24.400 us; speedup vs baseline: 1.1059x; 1.0636x over previous
//
#include <hip/hip_runtime.h>

// LBP forward: out[n,f,h,w] = sum_p 2^p * sigmoid((nb - ctr)/0.1)
//   c  = projection_map[f,p]; ky,kx = kernels[f,p,:] in {0,1,2}
//   nb  = xpad[n,c,h+ky-1,w+kx-1]  (zero pad of 1), ctr = x[n,c,h,w]
// N=32 D=64 H=56 W=56 F=128 P=4
//
// Round-23 = round-19 VERBATIM (best of 23 rounds: 24.3us). r19 is the
// unique config combining: (a) fp16 image-pair packed tile (the one proven
// lever, -2.2us), (b) ROWS=7 f-iter amortization (14 outputs/f-iter/lane),
// (c) 256 blocks = full CU coverage via the z=2 f-split. The f-split's
// "double fetch" is L2-absorbed: twins differ by 128 in linear id -> same
// id%8 -> same XCD -> second fetch hits L2 (effective HBM ~36MB).
// r20/r21/r22 rebalanced bytes/blocks/amortization and all landed 26-27.
// Sigmoid: 3-tangent-line min in packed v_pk_fma/min_f16 (absmax 0.1875).

#define NN 32
#define DD 64
#define HH 56
#define WW 56
#define FF 128
#define PP 4

#define ROWS 7          // output rows per block
#define TR   (ROWS + 2) // 9 tile rows incl. halo
#define TC   64         // padded cols (interior 4..59, zero pads at 3 and 60)
#define COL0 4
#define CHS  (TR * TC)  // 576 dwords per channel (each dword = half2 pair)
#define TILE_DW (DD * CHS)   // 36864 dwords = 147456 B
#define NTHREADS 1024
#define NWAVES 16
#define NPAIR 16
#define NSTRIP (HH / ROWS)       // 8
#define FH 64                    // f per block (z-split)
#define FITER (FH / NWAVES)      // 4 f per wave
#define ITEMS (DD * TR * 14)     // 8064 staging items (2 float4 loads each)
#define IMGSTR (DD * HH * WW)    // floats per image

typedef _Float16 h2 __attribute__((ext_vector_type(2)));

static __device__ __forceinline__ uint32_t h2u(h2 h) {
    union { h2 h; uint32_t u; } v; v.h = h; return v.u;
}
static __device__ __forceinline__ h2 u2h(uint32_t u) {
    union { h2 h; uint32_t u; } v; v.u = u; return v.h;
}
static __device__ __forceinline__ h2 splat(float f) {
    h2 r; r.x = (_Float16)f; r.y = (_Float16)f; return r;
}
static __device__ __forceinline__ uint32_t pack2(float a, float b) {
    h2 r; r.x = (_Float16)a; r.y = (_Float16)b; return h2u(r);
}

__global__ __launch_bounds__(NTHREADS, 4) void lbp_kernel(
    const float* __restrict__ x,    // (N,D,H,W)
    const int*   __restrict__ kern, // (F,P,2)
    const int*   __restrict__ proj, // (F,P)
    float*       __restrict__ out)  // (N,F,H,W)
{
    __shared__ uint32_t tile[TILE_DW];   // 147456 B, 1 block/CU

    const int tid = threadIdx.x;
    const int pr  = blockIdx.x;          // pair: images (pr, pr+16); XCD pin
    const int h0  = blockIdx.y * ROWS;   // 0,7,...,49
    const int fh  = blockIdx.z;          // 0..1 -> f base

    const float* x0 = x + (size_t)pr * IMGSTR;
    const float* x1 = x0 + (size_t)NPAIR * IMGSTR;

    // ---- stage: 8064 items, 8/thread; 2 float4 loads each, all up front ----
    float4 av[8], bv[8];
    int    lo[8];
#pragma unroll
    for (int it = 0; it < 8; ++it) {
        const int item = tid + it * NTHREADS;
        av[it] = make_float4(0.f, 0.f, 0.f, 0.f);
        bv[it] = make_float4(0.f, 0.f, 0.f, 0.f);
        lo[it] = -1;
        if (item < ITEMS) {                       // only it==7 is partial
            const int ch  = item / (TR * 14);
            const int rem = item - ch * (TR * 14);
            const int tr  = rem / 14;
            const int v   = rem - tr * 14;
            lo[it] = ch * CHS + tr * TC + COL0 + 4 * v;
            const int h = h0 + tr - 1;
            if ((unsigned)h < (unsigned)HH) {
                const int off = ch * (HH * WW) + h * WW + 4 * v;
                av[it] = *(const float4*)(x0 + off);
                bv[it] = *(const float4*)(x1 + off);
            }
        }
    }

    // ---- zero the kx-pad columns (3 and 60) while loads fly ----
    for (int i = tid; i < DD * TR * 2; i += NTHREADS) {
        const int ch   = i / (TR * 2);
        const int rr   = (i >> 1) % TR;
        const int side = i & 1;
        tile[ch * CHS + rr * TC + 3 + side * 57] = 0u;
    }

    // ---- pack (img0 = lo half, img1 = hi half) and land b128 ----
#pragma unroll
    for (int it = 0; it < 8; ++it) {
        if (lo[it] >= 0) {
            uint4 q;
            q.x = pack2(av[it].x, bv[it].x);
            q.y = pack2(av[it].y, bv[it].y);
            q.z = pack2(av[it].z, bv[it].z);
            q.w = pack2(av[it].w, bv[it].w);
            *(uint4*)(tile + lo[it]) = q;         // 16B aligned (COL0+4v)
        }
    }
    __syncthreads();

    // ---- compute: wave = f-group, lane = column, 7 rows x 2 images ----
    const int wid  = __builtin_amdgcn_readfirstlane(tid >> 6);  // 0..15
    const int lane = tid & 63;
    const int w    = lane < WW ? lane : WW - 1;  // clamp idle lanes
    const bool act = lane < WW;
    const int cb   = TC + COL0 + w;              // ctr addr of output row 0

    const h2 K0a = splat(2.5f),     K0b = splat(-0.0078f);
    const h2 K1a = splat(1.49146f), K1b = splat(0.08455f);
    const h2 K2a = splat(0.45177f), K2b = splat(0.30774f);
    const h2 KF  = splat(0.49140f);
    const h2 INI = splat(7.5f);                  // sum wt*0.5 over all taps

    int f = fh * FH + wid;
    int4 pj = *(const int4*)(proj + f * PP);
    int4 ka = *(const int4*)(kern + f * (PP * 2));
    int4 kb = *(const int4*)(kern + f * (PP * 2) + 4);

#pragma unroll
    for (int k = 0; k < FITER; ++k) {
        const int fn = f + NWAVES;
        int4 pjn = pj, kan = ka, kbn = kb;       // initialized (no UB)
        if (k + 1 < FITER) {                     // one-ahead table prefetch
            pjn = *(const int4*)(proj + fn * PP);
            kan = *(const int4*)(kern + fn * (PP * 2));
            kbn = *(const int4*)(kern + fn * (PP * 2) + 4);
        }
        const int cc[4]  = {pj.x, pj.y, pj.z, pj.w};
        const int kyv[4] = {ka.x, ka.z, kb.x, kb.z};
        const int kxv[4] = {ka.y, ka.w, kb.y, kb.w};

        // ---- bulk packed reads: skip center taps; one lgkmcnt join ----
        uint32_t cu[PP][ROWS], nu[PP][ROWS];
#pragma unroll
        for (int p = 0; p < PP; ++p) {
            const int ky = kyv[p];               // wave-uniform
            const int kx = kxv[p];
            if (!(ky == 1 && kx == 1)) {
                const int pc = cc[p] * CHS + cb;               // ctr row 0
                const int pn = pc + (ky - 1) * TC + (kx - 1);  // neighbor
#pragma unroll
                for (int r = 0; r < ROWS; ++r) {
                    cu[p][r] = tile[pc + r * TC];
                    nu[p][r] = tile[pn + r * TC];
                }
            }
        }

        // ---- packed trans-free sigmoid: ~6 pk-ops per eval-pair ----
        h2 acc[ROWS];
#pragma unroll
        for (int r = 0; r < ROWS; ++r) acc[r] = INI;
#pragma unroll
        for (int p = 0; p < PP; ++p) {
            if (!(kyv[p] == 1 && kxv[p] == 1)) {
                const h2 wt2 = splat((float)(1 << p));
#pragma unroll
                for (int r = 0; r < ROWS; ++r) {
                    const h2 d  = u2h(nu[p][r]) - u2h(cu[p][r]);
                    const uint32_t du = h2u(d);
                    const h2 ad = u2h(du & 0x7FFF7FFFu);
                    const h2 u0 = __builtin_elementwise_fma(K0a, ad, K0b);
                    const h2 u1 = __builtin_elementwise_fma(K1a, ad, K1b);
                    const h2 u2 = __builtin_elementwise_fma(K2a, ad, K2b);
                    const h2 um = __builtin_elementwise_min(
                                      __builtin_elementwise_min(u0, u1),
                                      __builtin_elementwise_min(u2, KF));
                    const uint32_t su = (du & 0x80008000u)
                                      | (h2u(um) & 0x7FFF7FFFu);
                    acc[r] = __builtin_elementwise_fma(wt2, u2h(su), acc[r]);
                }
            }
        }

        if (act) {
            float* o0 = out + ((size_t)pr * FF + f) * (HH * WW)
                            + (size_t)h0 * WW + w;
            float* o1 = o0 + (size_t)NPAIR * FF * (HH * WW);
#pragma unroll
            for (int r = 0; r < ROWS; ++r) {
                o0[r * WW] = (float)acc[r].x;
                o1[r * WW] = (float)acc[r].y;
            }
        }
        f = fn; pj = pjn; ka = kan; kb = kbn;
    }
}

extern "C" void kernel_launch(void* const* d_in, const int* in_sizes, int n_in,
                              void* d_out, int out_size, void* d_ws, size_t ws_size,
                              hipStream_t stream) {
    const float* x    = (const float*)d_in[0];
    const int*   kern = (const int*)d_in[1];
    const int*   proj = (const int*)d_in[2];
    float*       out  = (float*)d_out;

    dim3 grid(NPAIR, NSTRIP, 2);   // x = pair (XCD pin), y = strip, z = f-half
    dim3 block(NTHREADS);
    lbp_kernel<<<grid, block, 0, stream>>>(x, kern, proj, out);
}